// Round 1
// baseline (139.721 us; speedup 1.0000x reference)
//
#include <hip/hip_runtime.h>
#include <stdint.h>

#define BN_ 8192
#define DK_ 256

typedef __attribute__((ext_vector_type(4))) float f32x4;
typedef __attribute__((ext_vector_type(8))) short short8;
typedef __attribute__((ext_vector_type(8))) __bf16 bf16x8;
typedef __attribute__((ext_vector_type(4))) unsigned short us4;

// RNE float -> bf16 (no NaN handling needed; inputs are finite)
__device__ __forceinline__ unsigned short f2bf(float f) {
  unsigned u = __float_as_uint(f);
  u = (u + 0x7fffu + ((u >> 16) & 1u)) >> 16;
  return (unsigned short)u;
}

// async global->LDS, 16B per lane (wave-uniform LDS base + lane*16 layout)
#define GLD16(gp, lp)                                                   \
  __builtin_amdgcn_global_load_lds(                                     \
      (__attribute__((address_space(1))) void*)(gp),                    \
      (__attribute__((address_space(3))) void*)(lp), 16, 0, 0)

// ---------------- Kernel 1: row-normalize fp32 -> bf16 ----------------
// one wave per row; lane holds float4 (16B) of the 256-wide row
__global__ __launch_bounds__(256) void norm_kernel(
    const float* __restrict__ hf, const float* __restrict__ lf,
    const float* __restrict__ af,
    unsigned short* __restrict__ hn, unsigned short* __restrict__ ln,
    unsigned short* __restrict__ an) {
  const int tid = threadIdx.x;
  const int w = tid >> 6, lane = tid & 63;
  const int grow = blockIdx.x * 4 + w;       // 0..24575
  const int m = grow >> 13;                  // which matrix
  const int r = grow & (BN_ - 1);
  const float* src = (m == 0) ? hf : (m == 1) ? lf : af;
  unsigned short* dst = (m == 0) ? hn : (m == 1) ? ln : an;
  const float4 v = ((const float4*)(src + (size_t)r * DK_))[lane];
  float ss = v.x * v.x + v.y * v.y + v.z * v.z + v.w * v.w;
#pragma unroll
  for (int mk = 32; mk >= 1; mk >>= 1) ss += __shfl_xor(ss, mk, 64);
  const float inv = 1.0f / fmaxf(sqrtf(ss), 1e-8f);
  us4 o;
  o.x = f2bf(v.x * inv);
  o.y = f2bf(v.y * inv);
  o.z = f2bf(v.z * inv);
  o.w = f2bf(v.w * inv);
  *(us4*)(dst + (size_t)r * DK_ + lane * 4) = o;
}

// ---------------- Kernel 2: fused GEMM + exp-row-sum + diag ----------------
// grid = 2 pairs * 64 row-tiles * 16 col-chunks = 2048 blocks
// block: 128 rows x 512 cols (4 col-tiles of 128), K=256 via 4 x BK=64
// 4 waves (2x2), wave tile 64x64 = 4x4 frags of 16x16x32 bf16 MFMA
__global__ __launch_bounds__(256, 2) void gemm_lse_kernel(
    const unsigned short* __restrict__ hn, const unsigned short* __restrict__ ln,
    const unsigned short* __restrict__ an,
    float* __restrict__ sumexp /*[2][8192]*/, float* __restrict__ diag /*[2][8192]*/) {
  __shared__ __align__(16) unsigned short As[128 * 64];  // 16 KB
  __shared__ __align__(16) unsigned short Bs[128 * 64];  // 16 KB

  const int tid = threadIdx.x;
  const int lane = tid & 63, w = tid >> 6;
  const int wr = w >> 1, wc = w & 1;
  const int lmod = lane & 15, lhalf = lane >> 4;

  int b = blockIdx.x;
  const int p = b & 1;  b >>= 1;
  const int rt = b & 63; b >>= 6;
  const int cc = b;                      // 0..15
  const int r0 = rt * 128;
  const int c0 = cc * 512;

  const unsigned short* Asrc = p ? ln : hn;

  float rsum[4][4];
#pragma unroll
  for (int m = 0; m < 4; ++m)
#pragma unroll
    for (int r = 0; r < 4; ++r) rsum[m][r] = 0.0f;

  for (int ct = 0; ct < 4; ++ct) {
    const int cbase = c0 + ct * 128;
    f32x4 acc[4][4];
#pragma unroll
    for (int m = 0; m < 4; ++m)
#pragma unroll
      for (int n = 0; n < 4; ++n) acc[m][n] = f32x4{0.f, 0.f, 0.f, 0.f};

    for (int kt = 0; kt < 4; ++kt) {
      __syncthreads();  // previous compute done before overwriting LDS
#pragma unroll
      for (int q = 0; q < 4; ++q) {
        const int seg = q * 256 + tid;   // 16B segment index within tile
        const int row = seg >> 3;        // 0..127
        const int kk = (seg & 7) * 8;    // 0..56
        GLD16(Asrc + (size_t)(r0 + row) * DK_ + kt * 64 + kk, &As[seg * 8]);
        GLD16(an + (size_t)(cbase + row) * DK_ + kt * 64 + kk, &Bs[seg * 8]);
      }
      __syncthreads();  // compiler drains vmcnt(0) before barrier

#pragma unroll
      for (int ks = 0; ks < 2; ++ks) {
        bf16x8 afr[4], bfr[4];
#pragma unroll
        for (int m = 0; m < 4; ++m)
          afr[m] = __builtin_bit_cast(
              bf16x8, *(const short8*)&As[(wr * 64 + m * 16 + lmod) * 64 + ks * 32 + lhalf * 8]);
#pragma unroll
        for (int n = 0; n < 4; ++n)
          bfr[n] = __builtin_bit_cast(
              bf16x8, *(const short8*)&Bs[(wc * 64 + n * 16 + lmod) * 64 + ks * 32 + lhalf * 8]);
#pragma unroll
        for (int m = 0; m < 4; ++m)
#pragma unroll
          for (int n = 0; n < 4; ++n)
            acc[m][n] = __builtin_amdgcn_mfma_f32_16x16x32_bf16(afr[m], bfr[n], acc[m][n], 0, 0, 0);
      }
    }

    // diagonal extraction: this col-tile aligns with the row tile
    if (cbase == r0 && wr == wc) {
#pragma unroll
      for (int m = 0; m < 4; ++m)
#pragma unroll
        for (int r = 0; r < 4; ++r)
          if (lmod == lhalf * 4 + r)
            diag[p * BN_ + r0 + wr * 64 + m * 16 + lmod] = acc[m][m][r];
    }
    // exp and accumulate per-row partial sums (cols held by this lane)
#pragma unroll
    for (int m = 0; m < 4; ++m)
#pragma unroll
      for (int n = 0; n < 4; ++n)
#pragma unroll
        for (int r = 0; r < 4; ++r) rsum[m][r] += __expf(acc[m][n][r]);
  }

  // reduce across the 16 lanes (lmod) sharing each row, then one atomic
#pragma unroll
  for (int m = 0; m < 4; ++m)
#pragma unroll
    for (int r = 0; r < 4; ++r) {
      float v = rsum[m][r];
      v += __shfl_xor(v, 1, 64);
      v += __shfl_xor(v, 2, 64);
      v += __shfl_xor(v, 4, 64);
      v += __shfl_xor(v, 8, 64);
      if (lmod == 0)
        atomicAdd(&sumexp[p * BN_ + r0 + wr * 64 + m * 16 + lhalf * 4 + r], v);
    }
}

// ---------------- Kernel 3: CE = mean(log(sumexp) - diag), both pairs ----------------
__global__ __launch_bounds__(256) void finalize_kernel(
    const float* __restrict__ sumexp, const float* __restrict__ diag,
    float* __restrict__ out) {
  const int tid = threadIdx.x;
  float s = 0.0f;
  for (int i = tid; i < 2 * BN_; i += 256) s += logf(sumexp[i]) - diag[i];
#pragma unroll
  for (int mk = 32; mk >= 1; mk >>= 1) s += __shfl_xor(s, mk, 64);
  __shared__ float red[4];
  if ((tid & 63) == 0) red[tid >> 6] = s;
  __syncthreads();
  if (tid == 0) out[0] = (red[0] + red[1] + red[2] + red[3]) * (1.0f / (float)BN_);
}

extern "C" void kernel_launch(void* const* d_in, const int* in_sizes, int n_in,
                              void* d_out, int out_size, void* d_ws, size_t ws_size,
                              hipStream_t stream) {
  const float* hf = (const float*)d_in[0];
  const float* lf = (const float*)d_in[1];
  const float* af = (const float*)d_in[2];

  char* ws = (char*)d_ws;
  const size_t nmat = (size_t)BN_ * DK_;             // 2,097,152 elems
  unsigned short* hn = (unsigned short*)ws;          // 4 MB
  unsigned short* ln = hn + nmat;                    // 4 MB
  unsigned short* an = ln + nmat;                    // 4 MB
  float* sumexp = (float*)(ws + 3 * nmat * sizeof(unsigned short));  // 64 KB
  float* diag = sumexp + 2 * BN_;                                    // 64 KB

  hipMemsetAsync(sumexp, 0, 2 * BN_ * sizeof(float), stream);
  norm_kernel<<<(3 * BN_) / 4, 256, 0, stream>>>(hf, lf, af, hn, ln, an);
  gemm_lse_kernel<<<2048, 256, 0, stream>>>(hn, ln, an, sumexp, diag);
  finalize_kernel<<<1, 256, 0, stream>>>(sumexp, diag, (float*)d_out);
}

// Round 3
// 136.436 us; speedup vs baseline: 1.0241x; 1.0241x over previous
//
#include <hip/hip_runtime.h>
#include <stdint.h>

#define BN_ 8192
#define DK_ 256
#define LOG2E 1.4426950408889634f
#define LN2 0.6931471805599453f

typedef __attribute__((ext_vector_type(4))) float f32x4;
typedef __attribute__((ext_vector_type(8))) short short8;
typedef __attribute__((ext_vector_type(8))) __bf16 bf16x8;
typedef __attribute__((ext_vector_type(4))) unsigned short us4;

// RNE float -> bf16
__device__ __forceinline__ unsigned short f2bf(float f) {
  unsigned u = __float_as_uint(f);
  u = (u + 0x7fffu + ((u >> 16) & 1u)) >> 16;
  return (unsigned short)u;
}

// async global->LDS, 16B/lane; LDS dest must be wave-uniform base + lane*16
#define GLD16(gp, lp)                                                   \
  __builtin_amdgcn_global_load_lds(                                     \
      (__attribute__((address_space(1))) void*)(gp),                    \
      (__attribute__((address_space(3))) void*)(lp), 16, 0, 0)

// fused drain+barrier: single asm so no memory op is scheduled between
#define VMBAR() asm volatile("s_waitcnt vmcnt(0)\n\ts_barrier" ::: "memory")

// ---------------- Kernel 1: row-normalize fp32 -> bf16 (h,l scaled by log2e) ----------------
__global__ __launch_bounds__(256) void norm_kernel(
    const float* __restrict__ hf, const float* __restrict__ lf,
    const float* __restrict__ af,
    unsigned short* __restrict__ hn, unsigned short* __restrict__ ln,
    unsigned short* __restrict__ an) {
  const int tid = threadIdx.x;
  const int w = tid >> 6, lane = tid & 63;
  const int grow = blockIdx.x * 4 + w;       // 0..24575
  const int m = grow >> 13;                  // which matrix
  const int r = grow & (BN_ - 1);
  const float* src = (m == 0) ? hf : (m == 1) ? lf : af;
  unsigned short* dst = (m == 0) ? hn : (m == 1) ? ln : an;
  const float4 v = ((const float4*)(src + (size_t)r * DK_))[lane];
  float ss = v.x * v.x + v.y * v.y + v.z * v.z + v.w * v.w;
#pragma unroll
  for (int mk = 32; mk >= 1; mk >>= 1) ss += __shfl_xor(ss, mk, 64);
  float inv = 1.0f / fmaxf(sqrtf(ss), 1e-8f);
  if (m != 2) inv *= LOG2E;   // fold exp->exp2 conversion into one operand
  us4 o;
  o.x = f2bf(v.x * inv);
  o.y = f2bf(v.y * inv);
  o.z = f2bf(v.z * inv);
  o.w = f2bf(v.w * inv);
  *(us4*)(dst + (size_t)r * DK_ + lane * 4) = o;
}

// ---------------- Kernel 2: fused GEMM + exp2-row-sum + diag ----------------
// View A = [hn; ln] stacked: [16384, 256]. B = an: [8192, 256]. S = A·B^T.
// 256 blocks (1/CU), 512 threads (8 waves, 2M x 4N), tile 256x256, BK=64.
// Each block: fixed mt (row panel), streams 8 col-tiles (nt = cg*8 + i),
// 32 pipelined K-steps total, 1 barrier per step, vmcnt(0) waits only the
// already-needed stage. LDS XOR-swizzled (T2) via pre-swizzled global source.
__global__ __launch_bounds__(512, 2) void gemm_lse_kernel(
    const unsigned short* __restrict__ hl,   // [16384][256] stacked
    const unsigned short* __restrict__ an,   // [8192][256]
    float* __restrict__ sumexp /*[2][8192]*/, float* __restrict__ diag /*[2][8192]*/) {
  extern __shared__ unsigned short lds[];    // [2 buf][A 32KB | B 32KB] = 128KB

  const int tid = threadIdx.x;
  const int lane = tid & 63, w = tid >> 6;
  const int wr = w >> 2, wc = w & 3;         // 2M x 4N wave grid
  const int lmod = lane & 15, lhalf = lane >> 4;

  // XCD-grouping swizzle: all 4 cg-siblings of an mt land on one XCD
  const int bid = blockIdx.x;
  const int swz = (bid & 7) * 32 + (bid >> 3);   // bijective on 256
  const int mt = swz >> 2;                       // 0..63 row tile
  const int cg = swz & 3;                        // col group (8 nt each)

  // ---- staging geometry (loop-invariant per thread) ----
  // seg = q*512 + tid; row = q*64 + (tid>>3); sub = tid&7
  // swizzle: phys_byte P holds logical byte L = P ^ ((row&7)<<4)
  const int srow = tid >> 3;
  const int koff = ((tid & 7) * 16) ^ ((srow & 7) << 4);
  const char* aB = (const char*)hl + ((size_t)(mt * 256 + srow) * 512 + koff);
  const char* bB = (const char*)an + ((size_t)srow * 512 + koff);
  char* ldsb = (char*)lds;

#define STAGE(sn)                                                       \
  do {                                                                  \
    const int ktn = (sn) & 3;                                           \
    const int ntn = cg * 8 + ((sn) >> 2);                               \
    char* da = ldsb + (((sn) & 1) << 16) + (tid << 4);                  \
    const char* ga = aB + ktn * 128;                                    \
    const char* gb = bB + (size_t)ntn * 131072 + ktn * 128;             \
    GLD16(ga, da);                                                      \
    GLD16(ga + 32768, da + 8192);                                       \
    GLD16(ga + 65536, da + 16384);                                      \
    GLD16(ga + 98304, da + 24576);                                      \
    GLD16(gb, da + 32768);                                              \
    GLD16(gb + 32768, da + 40960);                                      \
    GLD16(gb + 65536, da + 49152);                                      \
    GLD16(gb + 98304, da + 57344);                                      \
  } while (0)

  const int xr = (lmod & 7) << 4;   // read-side swizzle (row&7 == lmod&7)

  float rsum[8][4];
#pragma unroll
  for (int m = 0; m < 8; ++m)
#pragma unroll
    for (int r = 0; r < 4; ++r) rsum[m][r] = 0.0f;

  STAGE(0);   // prologue

#pragma unroll 1
  for (int i = 0; i < 8; ++i) {
    f32x4 acc[8][4];
#pragma unroll
    for (int m = 0; m < 8; ++m)
#pragma unroll
      for (int n = 0; n < 4; ++n) acc[m][n] = f32x4{0.f, 0.f, 0.f, 0.f};

#pragma unroll
    for (int kt = 0; kt < 4; ++kt) {
      VMBAR();   // my step-s loads landed; everyone past compute(s-1)
      const int s = i * 4 + kt;
      if (kt < 3 || i < 7) STAGE(s + 1);   // in flight under compute(s)

      const unsigned short* As = lds + ((kt & 1) * 32768);
      const unsigned short* Bs = As + 16384;
#pragma unroll
      for (int ks = 0; ks < 2; ++ks) {
        const int kbyte = (ks * 64 + lhalf * 16) ^ xr;
        bf16x8 afr[8];
#pragma unroll
        for (int m = 0; m < 8; ++m) {
          const int arow = wr * 128 + m * 16 + lmod;
          afr[m] = __builtin_bit_cast(
              bf16x8, *(const short8*)((const char*)As + arow * 128 + kbyte));
        }
        bf16x8 bfr[4];
#pragma unroll
        for (int n = 0; n < 4; ++n) {
          const int brow = wc * 64 + n * 16 + lmod;
          bfr[n] = __builtin_bit_cast(
              bf16x8, *(const short8*)((const char*)Bs + brow * 128 + kbyte));
        }
#pragma unroll
        for (int m = 0; m < 8; ++m)
#pragma unroll
          for (int n = 0; n < 4; ++n)
            acc[m][n] = __builtin_amdgcn_mfma_f32_16x16x32_bf16(afr[m], bfr[n], acc[m][n], 0, 0, 0);
      }
    }

    // ---- tile epilogue: diag (rare) + exp2 accumulate into persistent rsum ----
    if (cg * 8 + i == (mt & 31)) {   // this tile holds the diagonal
#pragma unroll
      for (int m = 0; m < 8; ++m)
#pragma unroll
        for (int n = 0; n < 4; ++n)
#pragma unroll
          for (int r = 0; r < 4; ++r) {
            const int row_t = wr * 128 + m * 16 + lhalf * 4 + r;
            const int col_t = wc * 64 + n * 16 + lmod;
            if (row_t == col_t)
              diag[(mt >> 5) * BN_ + (mt & 31) * 256 + row_t] = acc[m][n][r] * LN2;
          }
    }
#pragma unroll
    for (int m = 0; m < 8; ++m)
#pragma unroll
      for (int n = 0; n < 4; ++n)
#pragma unroll
        for (int r = 0; r < 4; ++r)
          rsum[m][r] += exp2f(acc[m][n][r]);
  }

  // ---- final: reduce rsum across the 16 col-lanes, one atomic per row ----
#pragma unroll
  for (int m = 0; m < 8; ++m)
#pragma unroll
    for (int r = 0; r < 4; ++r) {
      float v = rsum[m][r];
      v += __shfl_xor(v, 1, 64);
      v += __shfl_xor(v, 2, 64);
      v += __shfl_xor(v, 4, 64);
      v += __shfl_xor(v, 8, 64);
      if (lmod == 0)
        atomicAdd(&sumexp[(mt >> 5) * BN_ + (mt & 31) * 256 + wr * 128 + m * 16 + lhalf * 4 + r], v);
    }
#undef STAGE
}

// ---------------- Kernel 3: CE = mean(log(sumexp) - diag) ----------------
__global__ __launch_bounds__(1024) void finalize_kernel(
    const float* __restrict__ sumexp, const float* __restrict__ diag,
    float* __restrict__ out) {
  const int tid = threadIdx.x;
  float s = 0.0f;
  for (int i = tid; i < 2 * BN_; i += 1024) s += logf(sumexp[i]) - diag[i];
#pragma unroll
  for (int mk = 32; mk >= 1; mk >>= 1) s += __shfl_xor(s, mk, 64);
  __shared__ float red[16];
  if ((tid & 63) == 0) red[tid >> 6] = s;
  __syncthreads();
  if (tid == 0) {
    float t = 0.f;
#pragma unroll
    for (int j = 0; j < 16; ++j) t += red[j];
    out[0] = t * (1.0f / (float)BN_);
  }
}

extern "C" void kernel_launch(void* const* d_in, const int* in_sizes, int n_in,
                              void* d_out, int out_size, void* d_ws, size_t ws_size,
                              hipStream_t stream) {
  const float* hf = (const float*)d_in[0];
  const float* lf = (const float*)d_in[1];
  const float* af = (const float*)d_in[2];

  char* ws = (char*)d_ws;
  const size_t nmat = (size_t)BN_ * DK_;
  unsigned short* hn = (unsigned short*)ws;          // 4 MB  (hn, ln contiguous = stacked A)
  unsigned short* ln = hn + nmat;                    // 4 MB
  unsigned short* an = ln + nmat;                    // 4 MB
  float* sumexp = (float*)(ws + 3 * nmat * sizeof(unsigned short));  // 64 KB
  float* diag = sumexp + 2 * BN_;                                    // 64 KB

  hipFuncSetAttribute((const void*)gemm_lse_kernel,
                      hipFuncAttributeMaxDynamicSharedMemorySize, 131072);

  hipMemsetAsync(sumexp, 0, 2 * BN_ * sizeof(float), stream);
  norm_kernel<<<(3 * BN_) / 4, 256, 0, stream>>>(hf, lf, af, hn, ln, an);
  gemm_lse_kernel<<<256, 512, 131072, stream>>>(hn, an, sumexp, diag);
  finalize_kernel<<<1, 1024, 0, stream>>>(sumexp, diag, (float*)d_out);
}

// Round 5
// 124.530 us; speedup vs baseline: 1.1220x; 1.0956x over previous
//
#include <hip/hip_runtime.h>
#include <stdint.h>

#define BN_ 8192
#define DK_ 256
#define LOG2E 1.4426950408889634f
#define LN2 0.6931471805599453f

typedef __attribute__((ext_vector_type(4))) float f32x4;
typedef __attribute__((ext_vector_type(8))) short short8;
typedef __attribute__((ext_vector_type(8))) __bf16 bf16x8;
typedef __attribute__((ext_vector_type(4))) unsigned short us4;

// RNE float -> bf16
__device__ __forceinline__ unsigned short f2bf(float f) {
  unsigned u = __float_as_uint(f);
  u = (u + 0x7fffu + ((u >> 16) & 1u)) >> 16;
  return (unsigned short)u;
}

// async global->LDS, 16B/lane; LDS dest wave-uniform base + lane*16, global src per-lane
#define GLD16(gp, lp)                                                   \
  __builtin_amdgcn_global_load_lds(                                     \
      (__attribute__((address_space(1))) void*)(gp),                    \
      (__attribute__((address_space(3))) void*)(lp), 16, 0, 0)

#define BAR() __builtin_amdgcn_s_barrier()
#define LGKM0() asm volatile("s_waitcnt lgkmcnt(0)" ::: "memory")
#define VM8() asm volatile("s_waitcnt vmcnt(8)" ::: "memory")

// ---------------- Kernel 1: row-normalize fp32 -> bf16 (h,l scaled by log2e) ----------------
__global__ __launch_bounds__(256) void norm_kernel(
    const float* __restrict__ hf, const float* __restrict__ lf,
    const float* __restrict__ af,
    unsigned short* __restrict__ hn, unsigned short* __restrict__ ln,
    unsigned short* __restrict__ an) {
  const int tid = threadIdx.x;
  const int w = tid >> 6, lane = tid & 63;
  const int grow = blockIdx.x * 4 + w;
  const int m = grow >> 13;
  const int r = grow & (BN_ - 1);
  const float* src = (m == 0) ? hf : (m == 1) ? lf : af;
  unsigned short* dst = (m == 0) ? hn : (m == 1) ? ln : an;
  const float4 v = ((const float4*)(src + (size_t)r * DK_))[lane];
  float ss = v.x * v.x + v.y * v.y + v.z * v.z + v.w * v.w;
#pragma unroll
  for (int mk = 32; mk >= 1; mk >>= 1) ss += __shfl_xor(ss, mk, 64);
  float inv = 1.0f / fmaxf(sqrtf(ss), 1e-8f);
  if (m != 2) inv *= LOG2E;
  us4 o;
  o.x = f2bf(v.x * inv);
  o.y = f2bf(v.y * inv);
  o.z = f2bf(v.z * inv);
  o.w = f2bf(v.w * inv);
  *(us4*)(dst + (size_t)r * DK_ + lane * 4) = o;
}

// ---------------- Kernel 2: fused GEMM + exp2-row-sum + diag, 8-phase pipelined ----------------
// A = [hn;ln] stacked [16384,256], B = an [8192,256], S = A·B^T.
// 256 blocks, 512 thr (8 waves 2Mx4N), tile 256x256, BK=64 (2 K-halves/step).
// LDS: 4-slot circular queue of K-half units (32KB = A16K + B16K row-interleaved,
// XOR-swizzled). Stages run ~5 phases ahead; vmcnt(8) counted gates at phases 1,3.
__global__ __launch_bounds__(512, 2) void gemm_lse_kernel(
    const unsigned short* __restrict__ hl, const unsigned short* __restrict__ an,
    float* __restrict__ sumexp, float* __restrict__ diag) {
  extern __shared__ char lds[];  // 4 * 32KB = 128KB

  const int tid = threadIdx.x;
  const int lane = tid & 63, w = tid >> 6;
  const int wr = w >> 2, wc = w & 3;
  const int lmod = lane & 15, lhalf = lane >> 4;

  const int bid = blockIdx.x;
  const int swz = (bid & 7) * 32 + (bid >> 3);  // bijective on 256, XCD-grouping
  const int mt = swz >> 2;                      // row tile 0..63
  const int cg = swz & 3;                       // col group (8 tiles each)

  // ---- stage-side per-thread constants ----
  // LDS pos o = w*4096 + j*1024 + lane*16 within slot: r=o>>7, h=(o>>6)&1, c=(o>>4)&3
  // holds (matrix = h^((r>>2)&1), row r, logical chunk = c^(r&3))
  const int isB = ((lane >> 2) ^ (lane >> 5)) & 1;
  const int lcst = (lane & 3) ^ ((lane >> 3) & 3);
  const int rbase = w * 32 + (lane >> 3);
  const char* myBase =
      (isB ? (const char*)an : (const char*)hl + (size_t)mt * 131072) +
      (size_t)rbase * 512 + lcst * 16;
  char* ldsW = lds + w * 4096 + lane * 16;

  // ---- read-side constants: logical (A,row ar,chunk lhalf) at
  // ar*128 + 64*((ar>>2)&1) + 16*(lhalf^(ar&3));  B: h-bit flipped
  const int xsw = 16 * (lhalf ^ (lmod & 3));
  const int aoff = wr * 16384 + lmod * 128 + 64 * ((lmod >> 2) & 1) + xsw;
  const int boff = wc * 8192 + lmod * 128 + 64 * (1 ^ ((lmod >> 2) & 1)) + xsw;

#define STAGE(uu)                                                        \
  do {                                                                   \
    const int u_ = (uu) & 63;                                            \
    const int kb_ = ((u_ >> 1) & 3) * 128 + (u_ & 1) * 64;               \
    const int nto_ = (cg * 8 + (u_ >> 3)) * 131072 + kb_;                \
    const char* s_ = myBase + (isB ? nto_ : kb_);                        \
    char* d_ = ldsW + ((uu) & 3) * 32768;                                \
    GLD16(s_, d_);                                                       \
    GLD16(s_ + 4096, d_ + 1024);                                         \
    GLD16(s_ + 8192, d_ + 2048);                                         \
    GLD16(s_ + 12288, d_ + 3072);                                        \
  } while (0)

#define LD8(dst, base, off)                                              \
  dst = __builtin_bit_cast(bf16x8, *(const short8*)((base) + (off)))

#define MFMA44(AF, BF, MB)                                               \
  _Pragma("unroll") for (int mm = 0; mm < 4; ++mm)                       \
  _Pragma("unroll") for (int nn = 0; nn < 4; ++nn)                       \
      acc[(MB) + mm][nn] = __builtin_amdgcn_mfma_f32_16x16x32_bf16(      \
          AF[mm], BF[nn], acc[(MB) + mm][nn], 0, 0, 0)

  float rsum[8][4];
#pragma unroll
  for (int m = 0; m < 8; ++m)
#pragma unroll
    for (int r = 0; r < 4; ++r) rsum[m][r] = 0.0f;

  // prologue: stage K-halves 0,1,2; gate u=0 (allow 1,2 in flight)
  STAGE(0);
  STAGE(1);
  STAGE(2);
  VM8();
  BAR();

#pragma unroll 1
  for (int i = 0; i < 8; ++i) {
    f32x4 acc[8][4];
#pragma unroll
    for (int m = 0; m < 8; ++m)
#pragma unroll
      for (int n = 0; n < 4; ++n) acc[m][n] = f32x4{0.f, 0.f, 0.f, 0.f};

#pragma unroll
    for (int kt = 0; kt < 4; ++kt) {
      const char* L0 = lds + ((kt & 1) * 2) * 32768;  // ks0 slot
      const char* L1 = L0 + 32768;                    // ks1 slot
      const int ub = 8 * i + 2 * kt;

      {  // ---- phase 0: ks0, m0-3 ----
        bf16x8 alo[4], bb[4];
#pragma unroll
        for (int m = 0; m < 4; ++m) LD8(alo[m], L0, aoff + m * 2048);
#pragma unroll
        for (int n = 0; n < 4; ++n) LD8(bb[n], L0, boff + n * 2048);
        STAGE(ub + 3);
        BAR();
        LGKM0();
        __builtin_amdgcn_s_setprio(1);
        MFMA44(alo, bb, 0);
        __builtin_amdgcn_s_setprio(0);
        BAR();
        // ---- phase 1: ks0, m4-7 ----
        bf16x8 ahi[4];
#pragma unroll
        for (int m = 0; m < 4; ++m) LD8(ahi[m], L0, aoff + (m + 4) * 2048);
        BAR();
        LGKM0();
        __builtin_amdgcn_s_setprio(1);
        MFMA44(ahi, bb, 4);
        __builtin_amdgcn_s_setprio(0);
        VM8();  // gate: next ks1 slot landed (2 K-halves stay in flight)
        BAR();
      }
      {  // ---- phase 2: ks1, m0-3 ----
        bf16x8 alo[4], bb[4];
#pragma unroll
        for (int m = 0; m < 4; ++m) LD8(alo[m], L1, aoff + m * 2048);
#pragma unroll
        for (int n = 0; n < 4; ++n) LD8(bb[n], L1, boff + n * 2048);
        STAGE(ub + 4);
        BAR();
        LGKM0();
        __builtin_amdgcn_s_setprio(1);
        MFMA44(alo, bb, 0);
        __builtin_amdgcn_s_setprio(0);
        BAR();
        // ---- phase 3: ks1, m4-7 ----
        bf16x8 ahi[4];
#pragma unroll
        for (int m = 0; m < 4; ++m) LD8(ahi[m], L1, aoff + (m + 4) * 2048);
        BAR();
        LGKM0();
        __builtin_amdgcn_s_setprio(1);
        MFMA44(ahi, bb, 4);
        __builtin_amdgcn_s_setprio(0);
        VM8();  // gate: next step's ks0 slot landed
        BAR();
      }
    }

    // ---- tile epilogue: diag (rare) + exp2 into persistent rsum ----
    if (cg * 8 + i == (mt & 31)) {
#pragma unroll
      for (int m = 0; m < 8; ++m)
#pragma unroll
        for (int n = 0; n < 4; ++n)
#pragma unroll
          for (int r = 0; r < 4; ++r) {
            const int row_t = wr * 128 + m * 16 + lhalf * 4 + r;
            const int col_t = wc * 64 + n * 16 + lmod;
            if (row_t == col_t)
              diag[(mt >> 5) * BN_ + (mt & 31) * 256 + row_t] = acc[m][n][r] * LN2;
          }
    }
#pragma unroll
    for (int m = 0; m < 8; ++m)
#pragma unroll
      for (int n = 0; n < 4; ++n)
#pragma unroll
        for (int r = 0; r < 4; ++r) rsum[m][r] += exp2f(acc[m][n][r]);
  }

  // ---- final: reduce across 16 col-lanes, one atomic per row ----
#pragma unroll
  for (int m = 0; m < 8; ++m)
#pragma unroll
    for (int r = 0; r < 4; ++r) {
      float v = rsum[m][r];
      v += __shfl_xor(v, 1, 64);
      v += __shfl_xor(v, 2, 64);
      v += __shfl_xor(v, 4, 64);
      v += __shfl_xor(v, 8, 64);
      if (lmod == 0)
        atomicAdd(&sumexp[(mt >> 5) * BN_ + (mt & 31) * 256 + wr * 128 + m * 16 + lhalf * 4 + r], v);
    }
#undef STAGE
#undef LD8
#undef MFMA44
}

// ---------------- Kernel 3: CE = mean(log(sumexp) - diag) ----------------
__global__ __launch_bounds__(1024) void finalize_kernel(
    const float* __restrict__ sumexp, const float* __restrict__ diag,
    float* __restrict__ out) {
  const int tid = threadIdx.x;
  float s = 0.0f;
  for (int i = tid; i < 2 * BN_; i += 1024) s += logf(sumexp[i]) - diag[i];
#pragma unroll
  for (int mk = 32; mk >= 1; mk >>= 1) s += __shfl_xor(s, mk, 64);
  __shared__ float red[16];
  if ((tid & 63) == 0) red[tid >> 6] = s;
  __syncthreads();
  if (tid == 0) {
    float t = 0.f;
#pragma unroll
    for (int j = 0; j < 16; ++j) t += red[j];
    out[0] = t * (1.0f / (float)BN_);
  }
}

extern "C" void kernel_launch(void* const* d_in, const int* in_sizes, int n_in,
                              void* d_out, int out_size, void* d_ws, size_t ws_size,
                              hipStream_t stream) {
  const float* hf = (const float*)d_in[0];
  const float* lf = (const float*)d_in[1];
  const float* af = (const float*)d_in[2];

  char* ws = (char*)d_ws;
  const size_t nmat = (size_t)BN_ * DK_;
  unsigned short* hn = (unsigned short*)ws;          // 4 MB (hn,ln contiguous = stacked A)
  unsigned short* ln = hn + nmat;                    // 4 MB
  unsigned short* an = ln + nmat;                    // 4 MB
  float* sumexp = (float*)(ws + 3 * nmat * sizeof(unsigned short));  // 64 KB
  float* diag = sumexp + 2 * BN_;                                    // 64 KB

  hipFuncSetAttribute((const void*)gemm_lse_kernel,
                      hipFuncAttributeMaxDynamicSharedMemorySize, 131072);

  hipMemsetAsync(sumexp, 0, 2 * BN_ * sizeof(float), stream);
  norm_kernel<<<(3 * BN_) / 4, 256, 0, stream>>>(hf, lf, af, hn, ln, an);
  gemm_lse_kernel<<<256, 512, 131072, stream>>>(hn, an, sumexp, diag);
  finalize_kernel<<<1, 1024, 0, stream>>>(sumexp, diag, (float*)d_out);
}